// Round 1
// baseline (2166.487 us; speedup 1.0000x reference)
//
#include <hip/hip_runtime.h>

#define NATOMS 50000
#define FDIM   128
#define EXDIM  64
#define NEDGE  500000
#define NPAIR  14

typedef _Float16 v8h __attribute__((ext_vector_type(8)));
typedef _Float16 v4h __attribute__((ext_vector_type(4)));
typedef float    v4f __attribute__((ext_vector_type(4)));

// Pair visiting order chosen to minimize segment reloads:
// steps: k0(0,0) k1(0,1) k4(0,2) | k5(1,2) k6(1,2) k2(1,1) k3(1,1) |
//        k12(3,1) k11(3,0) k10(3,3) k13(3,2) | k7(2,2) k8(2,2) k9(2,2)
// g loads: 4 (one per i), h loads: 7, ex: 1.
__constant__ int cK[14]  = {0,1,4,5,6,2,3,12,11,10,13,7,8,9};
__constant__ int cI[14]  = {0,0,0,1,1,1,1,3,3,3,3,2,2,2};
__constant__ int cJ[14]  = {0,1,2,2,2,1,1,1,0,3,2,2,2,2};
__constant__ int cLG[14] = {1,0,0,1,0,0,0,1,0,0,0,1,0,0};
__constant__ int cLH[14] = {1,1,1,0,0,1,0,0,1,1,1,0,0,0};

// W1 (14,320,256) fp32 -> W1T fp16 in MFMA-B-fragment tile order:
// W1T[k14][nt(16)][kc(10)][quad(4)][col(16)][j(8)]
//   element = W1[k14][kc*32+quad*8+j][nt*16+col]
__global__ __launch_bounds__(256) void prep_w1(const float* __restrict__ W1,
                                               _Float16* __restrict__ W1T) {
    int tid = blockIdx.x * 256 + threadIdx.x;
    if (tid >= 14*320*256) return;
    int n   = tid & 255;
    int t   = tid >> 8;
    int kk  = t % 320;
    int k14 = t / 320;
    float v = W1[tid];
    int dst = ((((k14*16 + (n>>4))*10 + (kk>>5))*4 + ((kk>>3)&3))*16 + (n&15))*8 + (kk&7);
    W1T[dst] = (_Float16)v;
}

__global__ __launch_bounds__(256) void hopping_main(
    const float* __restrict__ sfeat, const float* __restrict__ pfeat,
    const float* __restrict__ dfeat, const float* __restrict__ Sfeat,
    const int*  __restrict__ hop,   const float* __restrict__ darr,
    const float* __restrict__ exd,  const float* __restrict__ b1,
    const float* __restrict__ W2,   const float* __restrict__ b2,
    const _Float16* __restrict__ W1T, float* __restrict__ out)
{
    // LDS: g/h segments 64x128 fp16 (stride 136 -> 2-way bank alias only),
    // ex segment 64x64 (stride 72), plus reduction/out buffers. ~49.4 KB.
    __shared__ _Float16 gseg[64*136];
    __shared__ _Float16 hseg[64*136];
    __shared__ _Float16 exseg[64*72];
    __shared__ float    redbuf[4][64];
    __shared__ float    outbuf[64*14];
    __shared__ int      la1[64];
    __shared__ int      la2[64];
    __shared__ float    linv[64];

    const int  tid = threadIdx.x;
    const long e0  = (long)blockIdx.x * 64;

    if (tid < 64) {
        long eg = e0 + tid; if (eg >= NEDGE) eg = NEDGE - 1;
        la1[tid] = hop[2*eg];
        la2[tid] = hop[2*eg + 1];
        float dv = darr[eg];
        linv[tid] = 1.0f / (dv * dv);
    }
    // ex_d gather (no scaling), once per block
    {
        int er = tid >> 2, q = tid & 3;
        long eg = e0 + er; if (eg >= NEDGE) eg = NEDGE - 1;
        const float4* src = (const float4*)exd + eg * 16;
        #pragma unroll
        for (int r = 0; r < 4; ++r) {
            int c4 = r*4 + q;
            float4 v = src[c4];
            v4h hv; hv[0]=(_Float16)v.x; hv[1]=(_Float16)v.y;
                    hv[2]=(_Float16)v.z; hv[3]=(_Float16)v.w;
            *(v4h*)&exseg[er*72 + c4*4] = hv;
        }
    }

    const int lane = tid & 63;
    const int w    = tid >> 6;
    const int col  = lane & 15;
    const int quad = lane >> 4;

    #pragma unroll 1
    for (int step = 0; step < 14; ++step) {
        const int k14 = cK[step];

        if (cLG[step] | cLH[step]) {
            __syncthreads();   // prior MFMA reads of segments done
            if (cLG[step]) {
                int i = cI[step];
                const float* tab = (i==0)?sfeat:(i==1)?pfeat:(i==2)?dfeat:Sfeat;
                int er = tid >> 2, q = tid & 3;
                const float4* src = (const float4*)tab + (size_t)la1[er] * 32;
                float inv = linv[er];
                #pragma unroll
                for (int r = 0; r < 8; ++r) {
                    int c4 = r*4 + q;
                    float4 v = src[c4];
                    v4h hv; hv[0]=(_Float16)(v.x*inv); hv[1]=(_Float16)(v.y*inv);
                            hv[2]=(_Float16)(v.z*inv); hv[3]=(_Float16)(v.w*inv);
                    *(v4h*)&gseg[er*136 + c4*4] = hv;
                }
            }
            if (cLH[step]) {
                int j = cJ[step];
                const float* tab = (j==0)?sfeat:(j==1)?pfeat:(j==2)?dfeat:Sfeat;
                int er = tid >> 2, q = tid & 3;
                const float4* src = (const float4*)tab + (size_t)la2[er] * 32;
                float inv = linv[er];
                #pragma unroll
                for (int r = 0; r < 8; ++r) {
                    int c4 = r*4 + q;
                    float4 v = src[c4];
                    v4h hv; hv[0]=(_Float16)(v.x*inv); hv[1]=(_Float16)(v.y*inv);
                            hv[2]=(_Float16)(v.z*inv); hv[3]=(_Float16)(v.w*inv);
                    *(v4h*)&hseg[er*136 + c4*4] = hv;
                }
            }
            __syncthreads();
        }

        // ---- GEMM: H(64x256) = X(64x320) @ W1[k14](320x256), fp32 acc ----
        v4f acc[4][4];
        #pragma unroll
        for (int a = 0; a < 4; ++a)
            #pragma unroll
            for (int b = 0; b < 4; ++b)
                acc[a][b] = (v4f){0.f, 0.f, 0.f, 0.f};

        const _Float16* __restrict__ wb = W1T + (size_t)k14 * 81920;

        #pragma unroll
        for (int kc = 0; kc < 10; ++kc) {
            const _Float16* sb; int koff, strd;
            if (kc < 4)      { sb = gseg;  koff = kc*32;     strd = 136; }
            else if (kc < 8) { sb = hseg;  koff = (kc-4)*32; strd = 136; }
            else             { sb = exseg; koff = (kc-8)*32; strd = 72;  }

            v8h af[4];
            #pragma unroll
            for (int mt = 0; mt < 4; ++mt)
                af[mt] = *(const v8h*)&sb[(mt*16 + col)*strd + koff + quad*8];

            v8h bf[4];
            #pragma unroll
            for (int nt = 0; nt < 4; ++nt)
                bf[nt] = *(const v8h*)&wb[(((size_t)(w*4 + nt)*10 + kc)*64 + lane)*8];

            #pragma unroll
            for (int mt = 0; mt < 4; ++mt)
                #pragma unroll
                for (int nt = 0; nt < 4; ++nt)
                    acc[mt][nt] = __builtin_amdgcn_mfma_f32_16x16x32_f16(
                        af[mt], bf[nt], acc[mt][nt], 0, 0, 0);
        }

        // ---- epilogue: bias + leaky-relu + dot with W2, reduce over n ----
        float p[4][4] = {};
        #pragma unroll
        for (int nt = 0; nt < 4; ++nt) {
            int n = (w*4 + nt)*16 + col;
            float b1v = b1[k14*256 + n];
            float w2v = W2[k14*256 + n];
            #pragma unroll
            for (int mt = 0; mt < 4; ++mt)
                #pragma unroll
                for (int r = 0; r < 4; ++r) {
                    float hv = acc[mt][nt][r] + b1v;
                    hv = (hv > 0.f) ? hv : 0.01f * hv;
                    p[mt][r] += hv * w2v;
                }
        }
        #pragma unroll
        for (int mt = 0; mt < 4; ++mt)
            #pragma unroll
            for (int r = 0; r < 4; ++r) {
                float v = p[mt][r];
                v += __shfl_xor(v, 1, 16);
                v += __shfl_xor(v, 2, 16);
                v += __shfl_xor(v, 4, 16);
                v += __shfl_xor(v, 8, 16);
                if (col == 0) redbuf[w][mt*16 + quad*4 + r] = v;
            }
        __syncthreads();
        if (tid < 64)
            outbuf[tid*14 + k14] = redbuf[0][tid] + redbuf[1][tid] +
                                   redbuf[2][tid] + redbuf[3][tid] + b2[k14];
        __syncthreads();
    }

    // coalesced store of this block's 64x14 output slab
    for (int o = tid; o < 64*14; o += 256) {
        long g = e0*14 + o;
        if (g < (long)NEDGE*14) out[g] = outbuf[o];
    }
}

extern "C" void kernel_launch(void* const* d_in, const int* in_sizes, int n_in,
                              void* d_out, int out_size, void* d_ws, size_t ws_size,
                              hipStream_t stream)
{
    (void)in_sizes; (void)n_in; (void)out_size; (void)ws_size;
    const float* sfeat = (const float*)d_in[0];
    const float* pfeat = (const float*)d_in[1];
    const float* dfeat = (const float*)d_in[2];
    const float* Sfeat = (const float*)d_in[3];
    const int*   hop   = (const int*)  d_in[4];
    const float* darr  = (const float*)d_in[5];
    const float* exd   = (const float*)d_in[6];
    const float* W1    = (const float*)d_in[7];
    const float* b1    = (const float*)d_in[8];
    const float* W2    = (const float*)d_in[9];
    const float* b2    = (const float*)d_in[10];
    _Float16* W1T = (_Float16*)d_ws;   // 14*320*256*2 B = 2.29 MB

    // d_ws is re-poisoned before every timed call -> rebuild W1T every launch.
    prep_w1<<<dim3(4480), dim3(256), 0, stream>>>(W1, W1T);

    int nblk = (NEDGE + 63) / 64;   // 7813
    hopping_main<<<dim3(nblk), dim3(256), 0, stream>>>(
        sfeat, pfeat, dfeat, Sfeat, hop, darr, exd, b1, W2, b2, W1T, (float*)d_out);
}